// Round 11
// baseline (578.002 us; speedup 1.0000x reference)
//
#include <hip/hip_runtime.h>
#include <math.h>

#define NB 4096
#define NH 3
#define NK 32768
#define ND 128
#define KA 256           // A stored K: [rh(128) | rl(128)]
#define KB 256           // B stored K: [wh(128) | wl(128)]  (dedup: wh read twice via regs)
#define RB 128           // rows per block
#define CS 16            // column splits (2 per XCD)
#define CPB (NK / CS)    // 2048 cols per block
#define CI 128           // cols per col-iteration (4 col-groups x 32)
#define NCI (CPB / CI)   // 16 col-iterations per block (ci fits a nibble)

typedef _Float16 half8_t __attribute__((ext_vector_type(8)));
typedef _Float16 half2_t __attribute__((ext_vector_type(2)));
typedef float f32x4 __attribute__((ext_vector_type(4)));
typedef float f32x16 __attribute__((ext_vector_type(16)));
typedef __attribute__((address_space(1))) const unsigned int gu32_t;
typedef __attribute__((address_space(3))) unsigned int lu32_t;

#define MFMA32(A_, B_, C_) __builtin_amdgcn_mfma_f32_32x32x16_f16((A_), (B_), (C_), 0, 0, 0)

// ---------------------------------------------------------------------------
// init: resid = inputs, quantized = 0, loss = 0, rr = sum(resid^2), Aext row.
__global__ __launch_bounds__(64) void init_kernel(const float* __restrict__ inp,
                                                  float* __restrict__ resid,
                                                  float* __restrict__ rr,
                                                  float* __restrict__ out,
                                                  _Float16* __restrict__ Aext) {
  int row = blockIdx.x;
  int lane = threadIdx.x;
  const float2* ip = (const float2*)(inp + row * ND);
  float2 v = ip[lane];
  ((float2*)(resid + row * ND))[lane] = v;
  ((float2*)(out + NB + row * ND))[lane] = make_float2(0.f, 0.f);
  if (lane == 0) out[row] = 0.f; // loss
  _Float16 h0 = (_Float16)v.x, h1 = (_Float16)v.y;
  _Float16 l0 = (_Float16)(v.x - (float)h0), l1 = (_Float16)(v.y - (float)h1);
  half2_t h = {h0, h1}, l = {l0, l1};
  _Float16* base = Aext + (size_t)row * KA;
  *(half2_t*)(base + 2 * lane) = h;       // rh
  *(half2_t*)(base + 128 + 2 * lane) = l; // rl
  float s = v.x * v.x + v.y * v.y;
  #pragma unroll
  for (int m = 32; m; m >>= 1) s += __shfl_xor(s, m, 64);
  if (lane == 0) rr[row] = s;
}

// ---------------------------------------------------------------------------
// norms[row] = sum(W[row]^2) for all H*K rows (one wave per row), fp32 exact.
// NOTE: do NOT change this reduction tree — its rounding order is what the
// reference-matching argmax ties were validated against.
__global__ __launch_bounds__(256) void norms_kernel(const float* __restrict__ emb,
                                                    float* __restrict__ norms) {
  int row = blockIdx.x * 4 + (threadIdx.x >> 6);
  int lane = threadIdx.x & 63;
  const float2* wp = (const float2*)(emb + (size_t)row * ND);
  float2 v = wp[lane];
  float s = v.x * v.x + v.y * v.y;
  #pragma unroll
  for (int m = 32; m; m >>= 1) s += __shfl_xor(s, m, 64);
  if (lane == 0) norms[row] = s;
}

// ---------------------------------------------------------------------------
// fp32 -> (hi,lo) fp16 split for the 32x32x16 fragment layout (R9-verified).
// Bext per head: [group:1024 (32 cols)][ks:16][lane:64][8 f16]
//   ks 0..7 = wh ksteps (k = ks*16..+16), ks 8..15 = wl.
//   fragment lane l: col = group*32 + (l&31), k = ks*16 + (l>>5)*8 + j.
__global__ __launch_bounds__(256) void split_w_all_kernel(const float* __restrict__ emb,
                                                          _Float16* __restrict__ Bext) {
  const int head = blockIdx.x >> 10;      // 0..2
  const int g = blockIdx.x & 1023;        // col32 group
  const int coll = threadIdx.x & 31;
  const int idx = threadIdx.x >> 5;       // 0..7
  const int n = g * 32 + coll;

  _Float16* gb = Bext + (size_t)head * NK * KB + (size_t)g * 8192;
  const float* src = emb + (size_t)head * NK * ND + (size_t)n * ND;

  #pragma unroll
  for (int iter = 0; iter < 2; ++iter) {
    const int kh = idx + iter * 8; // 0..15 half-kstep
    const int ks = kh >> 1, hi = kh & 1;
    const int k = ks * 16 + hi * 8;
    const float4* wp = (const float4*)(src + k);
    float4 v0 = wp[0], v1 = wp[1];
    float xv[8] = {v0.x, v0.y, v0.z, v0.w, v1.x, v1.y, v1.z, v1.w};
    half8_t h, l;
    #pragma unroll
    for (int j = 0; j < 8; ++j) {
      _Float16 hh = (_Float16)xv[j];
      h[j] = hh;
      l[j] = (_Float16)(xv[j] - (float)hh);
    }
    const int lanef = hi * 32 + coll;
    *(half8_t*)(gb + ks * 512 + lanef * 8) = h;       // wh
    *(half8_t*)(gb + (8 + ks) * 512 + lanef * 8) = l; // wl
  }
}

// ---------------------------------------------------------------------------
// Barrier-free score kernel — R11: the R9-verified 32x32x16 fragment algebra
// in R8's geometry. R10 taught: CI=64 doubled per-ci overhead and cut load
// coverage to 3 MFMAs per B batch -> latency-bound at MfmaUtil 33%. Here:
// 8 waves = 2 row-halves x 4 col-groups (wr=wn>>2, wc=wn&3), each wave TWO
// stacked 32x32 tiles (64r x 32c), CI=128/NCI=16. Per ks: 2 B loads feed 6
// MFMAs (194cy), plus DISTANCE-1 B PREFETCH (load ks+1 during ks's MFMAs) so
// each load has a full MFMA batch + 3 other waves of cover.
// Register audit (R9's spill was bs[32]+vci[8]+unroll2 ~130): vci deleted
// (ci is wave-uniform -> s_lshl), pk nibble-packed [4] (NCI=16), single Q
// (tile1 = Q+16384: row+32 flips only the m*512 term), ks loop unroll 1.
// bs 32 + pk 4 + acc 32 + B 8 + Bnext 8 + Afrag 16 + misc ~12 ~= 112 < 128
// -> 4 waves/SIMD at __launch_bounds__(512,4), grid 512 = 2 blocks/CU.
// A LDS [m:128][slot:32][8f16], slot = chunk ^ (m&31): conflict-free reads
// (R10 measured 37.5k -> 4.1k). addr = Q ^ ks*32 ^ src*256 (disjoint bits).
// Fragment maps (R9 absmax=0): A/B lane l: row|col=l&31, k=(l>>5)*8+j;
// C: col=l&31, row=(reg&3)+8*(reg>>2)+4*(l>>5).
// Tie-break: one col per lane-slot per ci, ci descending => cidx strictly
// decreasing, ">=" keeps lowest index; cross-lane/block comparator
// (>, ==&&<) handles col ties. Matches jnp.argmax.
// bid&15 = col-split; 2 x 1 MB B slices per XCD's L2 (cs mod 8 == xcd).
__global__ __launch_bounds__(512, 4) void score_mfma_kernel(
    const _Float16* __restrict__ Aext, const _Float16* __restrict__ Bext,
    const float* __restrict__ rr, const float* __restrict__ normh,
    float* __restrict__ partial_s, int* __restrict__ partial_i) {
  __shared__ __align__(16) _Float16 Ash[RB * KA]; // 64 KB: [m:128][slot:32][8 f16]
  __shared__ __align__(16) float rrsh[RB];        // 512 B

  const int bid = blockIdx.x;
  const int cs = bid & (CS - 1);
  const int rowb = bid >> 4;
  const int rowBase = rowb * RB;
  const int colBase0 = cs * CPB;

  const int tid = threadIdx.x;
  const int lane = tid & 63;
  const int wn = tid >> 6; // wave 0..7
  const int wc = wn & 3;   // col-group (32 cols)
  const int wr = wn >> 2;  // row-half (2 x 32-row tiles)
  const int cl = lane & 31;
  const int hi = lane >> 5;

  // ---- stage A panel (once): wave wn stages rows wn*16..+16 (8 KB) ----
  // LDS[m][slot] = A[rowBase+m][chunk = slot ^ (m&31)]  (chunk = 8 f16)
  {
    #pragma unroll
    for (int i = 0; i < 8; ++i) {
      const int m0 = wn * 16 + i * 2;
      const int ml = m0 + hi;
      const int c = cl ^ (ml & 31);
      const _Float16* gA = Aext + (size_t)(rowBase + ml) * KA + c * 8;
      __builtin_amdgcn_global_load_lds((gu32_t*)gA, (lu32_t*)&Ash[m0 * 256], 16, 0, 0);
    }
  }
  if (tid < RB) rrsh[tid] = rr[rowBase + tid];

  // per-lane A byte address, tile0, even parity.
  // read addr = Q ^ (ks*32) ^ (src*256); tile1 = +16384 (row+32).
  int Q;
  {
    const int ml = wr * 64 + cl;
    Q = (ml * 512 + (ml & 31) * 16) ^ (hi * 16);
  }

  float bs[32];
  int pk[4];
  #pragma unroll
  for (int t = 0; t < 32; ++t) bs[t] = -INFINITY;
  #pragma unroll
  for (int t = 0; t < 4; ++t) pk[t] = 0;

  __syncthreads(); // the only barrier before the epilogue

  const f32x16 Z = {0.f, 0.f, 0.f, 0.f, 0.f, 0.f, 0.f, 0.f,
                    0.f, 0.f, 0.f, 0.f, 0.f, 0.f, 0.f, 0.f};
  const char* AshB = (const char*)Ash;

  #pragma unroll 1
  for (int ci = NCI - 1; ci >= 0; --ci) {
    const int ncol = colBase0 + ci * CI + wc * 32;
    const char* bp = (const char*)Bext +
                     ((unsigned)(ncol >> 5) * 16384u + (unsigned)lane * 16u);
    const float nw = normh[ncol + cl]; // issued early, used in fold

    f32x16 acc0, acc1;
    half8_t bh = *(const half8_t*)(bp);
    half8_t bl = *(const half8_t*)(bp + 8 * 1024);
    // ---- ks = 0, peeled: first MFMA pair consumes Z; prefetch ks1 ----
    {
      half8_t nh = *(const half8_t*)(bp + 1024);
      half8_t nl = *(const half8_t*)(bp + 9 * 1024);
      half8_t a0h = *(const half8_t*)(AshB + Q);
      half8_t a1h = *(const half8_t*)(AshB + Q + 16384);
      half8_t a0l = *(const half8_t*)(AshB + (Q ^ 256));
      half8_t a1l = *(const half8_t*)(AshB + ((Q ^ 256) + 16384));
      __builtin_amdgcn_s_setprio(1);
      acc0 = MFMA32(a0h, bh, Z);
      acc1 = MFMA32(a1h, bh, Z);
      acc0 = MFMA32(a0l, bh, acc0);
      acc1 = MFMA32(a1l, bh, acc1);
      acc0 = MFMA32(a0h, bl, acc0);
      acc1 = MFMA32(a1h, bl, acc1);
      __builtin_amdgcn_s_setprio(0);
      bh = nh;
      bl = nl;
    }
    // ---- ks = 1..7, distance-1 B prefetch (last iter reloads ks7: safe) --
    #pragma unroll 1
    for (int ks = 1; ks < 8; ++ks) {
      const int nxt = (ks < 7) ? ks + 1 : 7;
      half8_t nh = *(const half8_t*)(bp + nxt * 1024);
      half8_t nl = *(const half8_t*)(bp + (8 + nxt) * 1024);
      const int ax = ks * 32;
      half8_t a0h = *(const half8_t*)(AshB + (Q ^ ax));
      half8_t a1h = *(const half8_t*)(AshB + ((Q ^ ax) + 16384));
      half8_t a0l = *(const half8_t*)(AshB + (Q ^ ax ^ 256));
      half8_t a1l = *(const half8_t*)(AshB + ((Q ^ ax ^ 256) + 16384));
      __builtin_amdgcn_s_setprio(1);
      acc0 = MFMA32(a0h, bh, acc0);
      acc1 = MFMA32(a1h, bh, acc1);
      acc0 = MFMA32(a0l, bh, acc0);
      acc1 = MFMA32(a1l, bh, acc1);
      acc0 = MFMA32(a0h, bl, acc0);
      acc1 = MFMA32(a1h, bl, acc1);
      __builtin_amdgcn_s_setprio(0);
      bh = nh;
      bl = nl;
    }

    // ---- fold into running argmax (index = ci packed as a nibble) ----
    // One col per lane-slot, cidx strictly decreasing across ci, so ">="
    // keeps the lowest index, matching jnp.argmax.
#define FOLD_TILE(T_, ACC_)                                                     \
    _Pragma("unroll")                                                           \
    for (int g = 0; g < 4; ++g) {                                               \
      const f32x4 r4 = *(const f32x4*)&rrsh[wr * 64 + (T_)*32 + hi * 4 + g * 8];\
      _Pragma("unroll")                                                         \
      for (int j = 0; j < 4; ++j) {                                             \
        const int r = g * 4 + j;                                                \
        const int s = (T_)*16 + r;                                              \
        float t1 = r4[j] + nw;                     /* fl(rr + |w|^2), as ref */ \
        float v = fmaf(2.0f, (ACC_)[r], -t1);      /* == fl(2*acc - t1)     */  \
        bool u = (v >= bs[s]);                                                  \
        bs[s] = u ? v : bs[s];                                                  \
        const int sh = (s & 7) * 4;                                             \
        int upd = (pk[s >> 3] & ~(0xF << sh)) | (ci << sh);                     \
        pk[s >> 3] = u ? upd : pk[s >> 3];                                      \
      }                                                                         \
    }
    FOLD_TILE(0, acc0)
    FOLD_TILE(1, acc1)
#undef FOLD_TILE
  }

  // ---- block argmax reduction (overlay scratch on Ash) ----
  __syncthreads(); // all LDS A-reads complete
  float* red_s = (float*)Ash;      // [128][4]
  int* red_i = (int*)Ash + RB * 4; // [128][4]
  const int cbase = colBase0 + wc * 32 + cl;
  #pragma unroll
  for (int s = 0; s < 32; ++s) {
    float v = bs[s];
    int ciS = (pk[s >> 3] >> ((s & 7) * 4)) & 15;
    int ii = cbase + ciS * CI;
    // reduce over the 32 cols (each 32-lane half holds disjoint rows)
    #pragma unroll
    for (int mask = 1; mask <= 16; mask <<= 1) {
      float os = __shfl_xor(v, mask, 64);
      int oi = __shfl_xor(ii, mask, 64);
      if (os > v || (os == v && oi < ii)) { v = os; ii = oi; }
    }
    if (cl == 0) {
      const int t = s >> 4, r = s & 15;
      const int row = wr * 64 + t * 32 + (r & 3) + 8 * (r >> 2) + 4 * hi;
      red_s[row * 4 + wc] = v;
      red_i[row * 4 + wc] = ii;
    }
  }
  __syncthreads();
  if (tid < RB) {
    float s0 = red_s[tid * 4];
    int i0 = red_i[tid * 4];
    #pragma unroll
    for (int x = 1; x < 4; ++x) {
      float sx = red_s[tid * 4 + x];
      int ix = red_i[tid * 4 + x];
      if (sx > s0 || (sx == s0 && ix < i0)) { s0 = sx; i0 = ix; }
    }
    partial_s[(size_t)(rowBase + tid) * CS + cs] = s0;
    partial_i[(size_t)(rowBase + tid) * CS + cs] = i0;
  }
}

// ---------------------------------------------------------------------------
// Combine col-split partials -> code; resid -= W[c]; quantized += W[c];
// new rr; Aext row for next head.
__global__ __launch_bounds__(64) void reduce_update_kernel(const float* __restrict__ embh,
                                                           float* __restrict__ resid,
                                                           float* __restrict__ rr,
                                                           const float* __restrict__ ps,
                                                           const int* __restrict__ pi,
                                                           float* __restrict__ out,
                                                           _Float16* __restrict__ Aext, int h) {
  int row = blockIdx.x;
  int lane = threadIdx.x;
  float bs = -INFINITY;
  int bi = 0x7fffffff;
  if (lane < CS) {
    bs = ps[(size_t)row * CS + lane];
    bi = pi[(size_t)row * CS + lane];
  }
  #pragma unroll
  for (int m = 8; m; m >>= 1) {
    float os = __shfl_xor(bs, m, 64);
    int oi = __shfl_xor(bi, m, 64);
    if (os > bs || (os == bs && oi < bi)) { bs = os; bi = oi; }
  }
  int c = __shfl(bi, 0, 64);
  if (lane == 0) out[NB + NB * ND + row * NH + h] = (float)c; // codes as f32

  const float* wv = embh + (size_t)c * ND;
  float q0 = wv[lane], q1 = wv[lane + 64];
  float r0 = resid[row * ND + lane] - q0;
  float r1 = resid[row * ND + lane + 64] - q1;
  resid[row * ND + lane] = r0;
  resid[row * ND + lane + 64] = r1;
  out[NB + row * ND + lane] += q0;
  out[NB + row * ND + lane + 64] += q1;

  // Aext row for the next head (harmless extra work on the last head)
  _Float16 h0 = (_Float16)r0, l0 = (_Float16)(r0 - (float)h0);
  _Float16 h1 = (_Float16)r1, l1 = (_Float16)(r1 - (float)h1);
  _Float16* ab = Aext + (size_t)row * KA;
  ab[lane] = h0;       ab[lane + 64] = h1;       // rh
  ab[128 + lane] = l0; ab[128 + lane + 64] = l1; // rl

  float s = r0 * r0 + r1 * r1;
  #pragma unroll
  for (int m = 32; m; m >>= 1) s += __shfl_xor(s, m, 64);
  if (lane == 0) rr[row] = s;
}

// ---------------------------------------------------------------------------
extern "C" void kernel_launch(void* const* d_in, const int* in_sizes, int n_in,
                              void* d_out, int out_size, void* d_ws, size_t ws_size,
                              hipStream_t stream) {
  const float* inp = (const float*)d_in[0]; // (4096,1,128)
  const float* emb = (const float*)d_in[1]; // (3,32768,128)
  float* out = (float*)d_out;               // loss | quantized | codes

  float* resid = (float*)d_ws;                        // NB*ND f32
  float* rr = resid + NB * ND;                        // NB
  float* norms = rr + NB;                             // NH*NK
  float* ps = norms + NH * NK;                        // NB*CS f32
  int* pi = (int*)(ps + (size_t)NB * CS);             // NB*CS i32
  _Float16* Aext = (_Float16*)(pi + (size_t)NB * CS); // NB*KA f16
  _Float16* Bext = Aext + (size_t)NB * KA;            // NH*NK*KB f16 (~50 MB)

  hipLaunchKernelGGL(init_kernel, dim3(NB), dim3(64), 0, stream, inp, resid, rr, out, Aext);
  hipLaunchKernelGGL(norms_kernel, dim3(NH * NK / 4), dim3(256), 0, stream, emb, norms);
  hipLaunchKernelGGL(split_w_all_kernel, dim3(NH * NK / 32), dim3(256), 0, stream, emb, Bext);
  for (int h = 0; h < NH; ++h) {
    hipLaunchKernelGGL(score_mfma_kernel, dim3((NB / RB) * CS), dim3(512), 0, stream,
                       Aext, Bext + (size_t)h * NK * KB, rr, norms + (size_t)h * NK, ps, pi);
    hipLaunchKernelGGL(reduce_update_kernel, dim3(NB), dim3(64), 0, stream,
                       emb + (size_t)h * NK * ND, resid, rr, ps, pi, out, Aext, h);
  }
}

// Round 12
// 524.492 us; speedup vs baseline: 1.1020x; 1.1020x over previous
//
#include <hip/hip_runtime.h>
#include <math.h>

#define NB 4096
#define NH 3
#define NK 32768
#define ND 128
#define KA 256           // A stored K: [rh(128) | rl(128)]
#define KB 256           // B stored K: [wh(128) | wl(128)]  (dedup: wh read twice via regs)
#define RB 64            // rows per block (64: 32.5 KB LDS -> 4 blocks/CU resident)
#define CS 16            // column splits (2 per XCD)
#define CPB (NK / CS)    // 2048 cols per block
#define CI 128           // cols per col-iteration (4 col-groups x 32)
#define NCI (CPB / CI)   // 16 col-iterations per block (ci fits a nibble)

typedef _Float16 half8_t __attribute__((ext_vector_type(8)));
typedef _Float16 half2_t __attribute__((ext_vector_type(2)));
typedef float f32x4 __attribute__((ext_vector_type(4)));
typedef float f32x16 __attribute__((ext_vector_type(16)));
typedef __attribute__((address_space(1))) const unsigned int gu32_t;
typedef __attribute__((address_space(3))) unsigned int lu32_t;

#define MFMA32(A_, B_, C_) __builtin_amdgcn_mfma_f32_32x32x16_f16((A_), (B_), (C_), 0, 0, 0)

// ---------------------------------------------------------------------------
// init: resid = inputs, quantized = 0, loss = 0, rr = sum(resid^2), Aext row.
__global__ __launch_bounds__(64) void init_kernel(const float* __restrict__ inp,
                                                  float* __restrict__ resid,
                                                  float* __restrict__ rr,
                                                  float* __restrict__ out,
                                                  _Float16* __restrict__ Aext) {
  int row = blockIdx.x;
  int lane = threadIdx.x;
  const float2* ip = (const float2*)(inp + row * ND);
  float2 v = ip[lane];
  ((float2*)(resid + row * ND))[lane] = v;
  ((float2*)(out + NB + row * ND))[lane] = make_float2(0.f, 0.f);
  if (lane == 0) out[row] = 0.f; // loss
  _Float16 h0 = (_Float16)v.x, h1 = (_Float16)v.y;
  _Float16 l0 = (_Float16)(v.x - (float)h0), l1 = (_Float16)(v.y - (float)h1);
  half2_t h = {h0, h1}, l = {l0, l1};
  _Float16* base = Aext + (size_t)row * KA;
  *(half2_t*)(base + 2 * lane) = h;       // rh
  *(half2_t*)(base + 128 + 2 * lane) = l; // rl
  float s = v.x * v.x + v.y * v.y;
  #pragma unroll
  for (int m = 32; m; m >>= 1) s += __shfl_xor(s, m, 64);
  if (lane == 0) rr[row] = s;
}

// ---------------------------------------------------------------------------
// norms[row] = sum(W[row]^2) for all H*K rows (one wave per row), fp32 exact.
// NOTE: do NOT change this reduction tree — its rounding order is what the
// reference-matching argmax ties were validated against.
__global__ __launch_bounds__(256) void norms_kernel(const float* __restrict__ emb,
                                                    float* __restrict__ norms) {
  int row = blockIdx.x * 4 + (threadIdx.x >> 6);
  int lane = threadIdx.x & 63;
  const float2* wp = (const float2*)(emb + (size_t)row * ND);
  float2 v = wp[lane];
  float s = v.x * v.x + v.y * v.y;
  #pragma unroll
  for (int m = 32; m; m >>= 1) s += __shfl_xor(s, m, 64);
  if (lane == 0) norms[row] = s;
}

// ---------------------------------------------------------------------------
// fp32 -> (hi,lo) fp16 split for the 32x32x16 fragment layout (R9/R10-verified).
// Bext per head: [group:1024 (32 cols)][ks:16][lane:64][8 f16]
//   ks 0..7 = wh ksteps (k = ks*16..+16), ks 8..15 = wl.
//   fragment lane l: col = group*32 + (l&31), k = ks*16 + (l>>5)*8 + j.
__global__ __launch_bounds__(256) void split_w_all_kernel(const float* __restrict__ emb,
                                                          _Float16* __restrict__ Bext) {
  const int head = blockIdx.x >> 10;      // 0..2
  const int g = blockIdx.x & 1023;        // col32 group
  const int coll = threadIdx.x & 31;
  const int idx = threadIdx.x >> 5;       // 0..7
  const int n = g * 32 + coll;

  _Float16* gb = Bext + (size_t)head * NK * KB + (size_t)g * 8192;
  const float* src = emb + (size_t)head * NK * ND + (size_t)n * ND;

  #pragma unroll
  for (int iter = 0; iter < 2; ++iter) {
    const int kh = idx + iter * 8; // 0..15 half-kstep
    const int ks = kh >> 1, hi = kh & 1;
    const int k = ks * 16 + hi * 8;
    const float4* wp = (const float4*)(src + k);
    float4 v0 = wp[0], v1 = wp[1];
    float xv[8] = {v0.x, v0.y, v0.z, v0.w, v1.x, v1.y, v1.z, v1.w};
    half8_t h, l;
    #pragma unroll
    for (int j = 0; j < 8; ++j) {
      _Float16 hh = (_Float16)xv[j];
      h[j] = hh;
      l[j] = (_Float16)(xv[j] - (float)hh);
    }
    const int lanef = hi * 32 + coll;
    *(half8_t*)(gb + ks * 512 + lanef * 8) = h;       // wh
    *(half8_t*)(gb + (8 + ks) * 512 + lanef * 8) = l; // wl
  }
}

// ---------------------------------------------------------------------------
// Barrier-free score kernel — R12: R10's register shape (ONE 32x32 tile per
// wave: bs[16]+pk[2]+acc f32x16 ~= 60 regs, measured 52 in R10, no spill) in
// R8's iteration geometry (CI=128, NCI=16), with OCCUPANCY as latency cover.
// Spill ledger: R9/R11 proved 64 rows/wave (bs[32]+2 accs) can't fit 128
// regs; R10 proved 32 rows/wave fits in 52 but was latency-bound from
// NCI=32 overhead + 3-MFMA load bursts at only 4 waves/SIMD. Fix both:
//  - RB 128->64: 8 waves = 2 row-halves x 4 col-groups (wr=wn>>2, wc=wn&3)
//    keeps CI=128/NCI=16 with one tile/wave.
//  - LDS 32.5 KB -> 4 blocks/CU (grid 1024 = exactly 4/CU, tail-free); at
//    ~52-64 VGPR the HW fits 8 waves/SIMD -> per-B-batch cover = 8 x 96cy
//    ~= 770cy >> L2 latency (R10 had 384).
//  - Co-resident blocks bid, bid+256.. share one cs (256 % 16 == 0) -> one
//    1 MB B slice per CU in L2.
// A LDS [m:64][slot:32][8f16], slot = chunk ^ (m&31): conflict-free reads
// (R10 measured 37.5k -> 4.1k). addr = Q ^ ks*32 ^ src*256 (disjoint bits).
// Fragment maps (R9/R10 absmax=0): A/B lane l: row|col=l&31, k=(l>>5)*8+j;
// C: col=l&31, row=(reg&3)+8*(reg>>2)+4*(l>>5).
// Tie-break: one col per lane-slot per ci, ci descending => cidx strictly
// decreasing, ">=" keeps lowest index; cross-lane/block comparator
// (>, ==&&<) handles col ties. Matches jnp.argmax.
// bid&15 = col-split; 2 x 1 MB B slices per XCD's L2 (cs mod 8 == xcd).
__global__ __launch_bounds__(512, 4) void score_mfma_kernel(
    const _Float16* __restrict__ Aext, const _Float16* __restrict__ Bext,
    const float* __restrict__ rr, const float* __restrict__ normh,
    float* __restrict__ partial_s, int* __restrict__ partial_i) {
  __shared__ __align__(16) _Float16 Ash[RB * KA]; // 32 KB: [m:64][slot:32][8 f16]
  __shared__ __align__(16) float rrsh[RB];        // 256 B

  const int bid = blockIdx.x;
  const int cs = bid & (CS - 1);
  const int rowb = bid >> 4;
  const int rowBase = rowb * RB;
  const int colBase0 = cs * CPB;

  const int tid = threadIdx.x;
  const int lane = tid & 63;
  const int wn = tid >> 6; // wave 0..7
  const int wc = wn & 3;   // col-group (32 cols)
  const int wr = wn >> 2;  // row-half (32 rows)
  const int cl = lane & 31;
  const int hi = lane >> 5;

  // ---- stage A panel (once): wave wn stages rows wn*8..+8 (4 KB) ----
  // LDS[m][slot] = A[rowBase+m][chunk = slot ^ (m&31)]  (chunk = 8 f16)
  {
    #pragma unroll
    for (int i = 0; i < 4; ++i) {
      const int m0 = wn * 8 + i * 2;
      const int ml = m0 + hi;
      const int c = cl ^ (ml & 31);
      const _Float16* gA = Aext + (size_t)(rowBase + ml) * KA + c * 8;
      __builtin_amdgcn_global_load_lds((gu32_t*)gA, (lu32_t*)&Ash[m0 * 256], 16, 0, 0);
    }
  }
  if (tid < RB) rrsh[tid] = rr[rowBase + tid];

  // per-lane A byte address (even parity); read addr = Q ^ (ks*32) ^ (src*256)
  // addr = m*512 + (chunk ^ (m&31))*16, chunk = ks*2 + hi + src*16
  int Q;
  {
    const int ml = wr * 32 + cl;
    Q = (ml * 512 + (ml & 31) * 16) ^ (hi * 16);
  }

  float bs[16];
  int pk[2]; // 16 slots x 4-bit ci
  #pragma unroll
  for (int t = 0; t < 16; ++t) bs[t] = -INFINITY;
  pk[0] = 0;
  pk[1] = 0;

  __syncthreads(); // the only barrier before the epilogue

  const f32x16 Z = {0.f, 0.f, 0.f, 0.f, 0.f, 0.f, 0.f, 0.f,
                    0.f, 0.f, 0.f, 0.f, 0.f, 0.f, 0.f, 0.f};
  const char* AshB = (const char*)Ash;

  #pragma unroll 1
  for (int ci = NCI - 1; ci >= 0; --ci) {
    const int ncol = colBase0 + ci * CI + wc * 32;
    const char* bp = (const char*)Bext +
                     ((unsigned)(ncol >> 5) * 16384u + (unsigned)lane * 16u);
    const float nw = normh[ncol + cl]; // issued early, used in fold

    f32x16 acc;
    // ---- ks = 0, peeled: first MFMA consumes Z (no acc init) ----
    {
      half8_t bh = *(const half8_t*)(bp);
      half8_t bl = *(const half8_t*)(bp + 8 * 1024);
      half8_t ah = *(const half8_t*)(AshB + Q);
      half8_t al = *(const half8_t*)(AshB + (Q ^ 256));
      __builtin_amdgcn_s_setprio(1);
      acc = MFMA32(ah, bh, Z);
      acc = MFMA32(al, bh, acc);
      acc = MFMA32(ah, bl, acc);
      __builtin_amdgcn_s_setprio(0);
    }
    // ---- ks = 1..7 ----
    #pragma unroll 1
    for (int ks = 1; ks < 8; ++ks) {
      half8_t bh = *(const half8_t*)(bp + ks * 1024);
      half8_t bl = *(const half8_t*)(bp + (8 + ks) * 1024);
      half8_t ah = *(const half8_t*)(AshB + (Q ^ (ks * 32)));
      half8_t al = *(const half8_t*)(AshB + (Q ^ (ks * 32) ^ 256));
      __builtin_amdgcn_s_setprio(1);
      acc = MFMA32(ah, bh, acc);
      acc = MFMA32(al, bh, acc);
      acc = MFMA32(ah, bl, acc);
      __builtin_amdgcn_s_setprio(0);
    }

    // ---- fold into running argmax (index = ci packed as a nibble) ----
    // One col per lane-slot, cidx strictly decreasing across ci, so ">="
    // keeps the lowest index, matching jnp.argmax.
    #pragma unroll
    for (int g = 0; g < 4; ++g) {
      const f32x4 r4 = *(const f32x4*)&rrsh[wr * 32 + hi * 4 + g * 8];
      #pragma unroll
      for (int j = 0; j < 4; ++j) {
        const int s = g * 4 + j;
        float t1 = r4[j] + nw;              // fl(rr + |w|^2), as ref
        float v = fmaf(2.0f, acc[s], -t1);  // == fl(2*acc - t1)
        bool u = (v >= bs[s]);
        bs[s] = u ? v : bs[s];
        const int sh = (s & 7) * 4;
        int upd = (pk[s >> 3] & ~(0xF << sh)) | (ci << sh);
        pk[s >> 3] = u ? upd : pk[s >> 3];
      }
    }
  }

  // ---- block argmax reduction (overlay scratch on Ash) ----
  __syncthreads(); // all LDS A-reads complete
  float* red_s = (float*)Ash;      // [64][4]
  int* red_i = (int*)Ash + RB * 4; // [64][4]
  const int cbase = colBase0 + wc * 32 + cl;
  #pragma unroll
  for (int s = 0; s < 16; ++s) {
    float v = bs[s];
    int ciS = (pk[s >> 3] >> ((s & 7) * 4)) & 15;
    int ii = cbase + ciS * CI;
    // reduce over the 32 cols (each 32-lane half holds disjoint rows)
    #pragma unroll
    for (int mask = 1; mask <= 16; mask <<= 1) {
      float os = __shfl_xor(v, mask, 64);
      int oi = __shfl_xor(ii, mask, 64);
      if (os > v || (os == v && oi < ii)) { v = os; ii = oi; }
    }
    if (cl == 0) {
      const int row = wr * 32 + (s & 3) + 8 * (s >> 2) + 4 * hi;
      red_s[row * 4 + wc] = v;
      red_i[row * 4 + wc] = ii;
    }
  }
  __syncthreads();
  if (tid < RB) {
    float s0 = red_s[tid * 4];
    int i0 = red_i[tid * 4];
    #pragma unroll
    for (int x = 1; x < 4; ++x) {
      float sx = red_s[tid * 4 + x];
      int ix = red_i[tid * 4 + x];
      if (sx > s0 || (sx == s0 && ix < i0)) { s0 = sx; i0 = ix; }
    }
    partial_s[(size_t)(rowBase + tid) * CS + cs] = s0;
    partial_i[(size_t)(rowBase + tid) * CS + cs] = i0;
  }
}

// ---------------------------------------------------------------------------
// Combine col-split partials -> code; resid -= W[c]; quantized += W[c];
// new rr; Aext row for next head.
__global__ __launch_bounds__(64) void reduce_update_kernel(const float* __restrict__ embh,
                                                           float* __restrict__ resid,
                                                           float* __restrict__ rr,
                                                           const float* __restrict__ ps,
                                                           const int* __restrict__ pi,
                                                           float* __restrict__ out,
                                                           _Float16* __restrict__ Aext, int h) {
  int row = blockIdx.x;
  int lane = threadIdx.x;
  float bs = -INFINITY;
  int bi = 0x7fffffff;
  if (lane < CS) {
    bs = ps[(size_t)row * CS + lane];
    bi = pi[(size_t)row * CS + lane];
  }
  #pragma unroll
  for (int m = 8; m; m >>= 1) {
    float os = __shfl_xor(bs, m, 64);
    int oi = __shfl_xor(bi, m, 64);
    if (os > bs || (os == bs && oi < bi)) { bs = os; bi = oi; }
  }
  int c = __shfl(bi, 0, 64);
  if (lane == 0) out[NB + NB * ND + row * NH + h] = (float)c; // codes as f32

  const float* wv = embh + (size_t)c * ND;
  float q0 = wv[lane], q1 = wv[lane + 64];
  float r0 = resid[row * ND + lane] - q0;
  float r1 = resid[row * ND + lane + 64] - q1;
  resid[row * ND + lane] = r0;
  resid[row * ND + lane + 64] = r1;
  out[NB + row * ND + lane] += q0;
  out[NB + row * ND + lane + 64] += q1;

  // Aext row for the next head (harmless extra work on the last head)
  _Float16 h0 = (_Float16)r0, l0 = (_Float16)(r0 - (float)h0);
  _Float16 h1 = (_Float16)r1, l1 = (_Float16)(r1 - (float)h1);
  _Float16* ab = Aext + (size_t)row * KA;
  ab[lane] = h0;       ab[lane + 64] = h1;       // rh
  ab[128 + lane] = l0; ab[128 + lane + 64] = l1; // rl

  float s = r0 * r0 + r1 * r1;
  #pragma unroll
  for (int m = 32; m; m >>= 1) s += __shfl_xor(s, m, 64);
  if (lane == 0) rr[row] = s;
}

// ---------------------------------------------------------------------------
extern "C" void kernel_launch(void* const* d_in, const int* in_sizes, int n_in,
                              void* d_out, int out_size, void* d_ws, size_t ws_size,
                              hipStream_t stream) {
  const float* inp = (const float*)d_in[0]; // (4096,1,128)
  const float* emb = (const float*)d_in[1]; // (3,32768,128)
  float* out = (float*)d_out;               // loss | quantized | codes

  float* resid = (float*)d_ws;                        // NB*ND f32
  float* rr = resid + NB * ND;                        // NB
  float* norms = rr + NB;                             // NH*NK
  float* ps = norms + NH * NK;                        // NB*CS f32
  int* pi = (int*)(ps + (size_t)NB * CS);             // NB*CS i32
  _Float16* Aext = (_Float16*)(pi + (size_t)NB * CS); // NB*KA f16
  _Float16* Bext = Aext + (size_t)NB * KA;            // NH*NK*KB f16 (~50 MB)

  hipLaunchKernelGGL(init_kernel, dim3(NB), dim3(64), 0, stream, inp, resid, rr, out, Aext);
  hipLaunchKernelGGL(norms_kernel, dim3(NH * NK / 4), dim3(256), 0, stream, emb, norms);
  hipLaunchKernelGGL(split_w_all_kernel, dim3(NH * NK / 32), dim3(256), 0, stream, emb, Bext);
  for (int h = 0; h < NH; ++h) {
    hipLaunchKernelGGL(score_mfma_kernel, dim3((NB / RB) * CS), dim3(512), 0, stream,
                       Aext, Bext + (size_t)h * NK * KB, rr, norms + (size_t)h * NK, ps, pi);
    hipLaunchKernelGGL(reduce_update_kernel, dim3(NB), dim3(64), 0, stream,
                       emb + (size_t)h * NK * ND, resid, rr, ps, pi, out, Aext, h);
  }
}

// Round 13
// 507.058 us; speedup vs baseline: 1.1399x; 1.0344x over previous
//
#include <hip/hip_runtime.h>
#include <math.h>

#define NB 4096
#define NH 3
#define NK 32768
#define ND 128
#define KA 256           // A stored K: [rh(128) | rl(128)]
#define KB 256           // B stored K: [wh(128) | wl(128)]  (dedup: wh read twice via regs)
#define RB 64            // rows per block (64: 32.5 KB LDS -> 4 blocks/CU resident)
#define CS 16            // column splits (2 per XCD)
#define CPB (NK / CS)    // 2048 cols per block
#define CI 128           // cols per col-iteration (4 col-groups x 32)
#define NCI (CPB / CI)   // 16 col-iterations per block (ci fits a nibble)

typedef _Float16 half8_t __attribute__((ext_vector_type(8)));
typedef _Float16 half2_t __attribute__((ext_vector_type(2)));
typedef float f32x4 __attribute__((ext_vector_type(4)));
typedef float f32x16 __attribute__((ext_vector_type(16)));
typedef __attribute__((address_space(1))) const unsigned int gu32_t;
typedef __attribute__((address_space(3))) unsigned int lu32_t;

#define MFMA32(A_, B_, C_) __builtin_amdgcn_mfma_f32_32x32x16_f16((A_), (B_), (C_), 0, 0, 0)

// ---------------------------------------------------------------------------
// init: resid = inputs, quantized = 0, loss = 0, rr = sum(resid^2), Aext row.
__global__ __launch_bounds__(64) void init_kernel(const float* __restrict__ inp,
                                                  float* __restrict__ resid,
                                                  float* __restrict__ rr,
                                                  float* __restrict__ out,
                                                  _Float16* __restrict__ Aext) {
  int row = blockIdx.x;
  int lane = threadIdx.x;
  const float2* ip = (const float2*)(inp + row * ND);
  float2 v = ip[lane];
  ((float2*)(resid + row * ND))[lane] = v;
  ((float2*)(out + NB + row * ND))[lane] = make_float2(0.f, 0.f);
  if (lane == 0) out[row] = 0.f; // loss
  _Float16 h0 = (_Float16)v.x, h1 = (_Float16)v.y;
  _Float16 l0 = (_Float16)(v.x - (float)h0), l1 = (_Float16)(v.y - (float)h1);
  half2_t h = {h0, h1}, l = {l0, l1};
  _Float16* base = Aext + (size_t)row * KA;
  *(half2_t*)(base + 2 * lane) = h;       // rh
  *(half2_t*)(base + 128 + 2 * lane) = l; // rl
  float s = v.x * v.x + v.y * v.y;
  #pragma unroll
  for (int m = 32; m; m >>= 1) s += __shfl_xor(s, m, 64);
  if (lane == 0) rr[row] = s;
}

// ---------------------------------------------------------------------------
// norms[row] = sum(W[row]^2) for all H*K rows (one wave per row), fp32 exact.
// NOTE: do NOT change this reduction tree — its rounding order is what the
// reference-matching argmax ties were validated against.
__global__ __launch_bounds__(256) void norms_kernel(const float* __restrict__ emb,
                                                    float* __restrict__ norms) {
  int row = blockIdx.x * 4 + (threadIdx.x >> 6);
  int lane = threadIdx.x & 63;
  const float2* wp = (const float2*)(emb + (size_t)row * ND);
  float2 v = wp[lane];
  float s = v.x * v.x + v.y * v.y;
  #pragma unroll
  for (int m = 32; m; m >>= 1) s += __shfl_xor(s, m, 64);
  if (lane == 0) norms[row] = s;
}

// ---------------------------------------------------------------------------
// fp32 -> (hi,lo) fp16 split for the 32x32x16 fragment layout (R9/R10-verified).
// Bext per head: [group:1024 (32 cols)][ks:16][lane:64][8 f16]
//   ks 0..7 = wh ksteps (k = ks*16..+16), ks 8..15 = wl.
//   fragment lane l: col = group*32 + (l&31), k = ks*16 + (l>>5)*8 + j.
__global__ __launch_bounds__(256) void split_w_all_kernel(const float* __restrict__ emb,
                                                          _Float16* __restrict__ Bext) {
  const int head = blockIdx.x >> 10;      // 0..2
  const int g = blockIdx.x & 1023;        // col32 group
  const int coll = threadIdx.x & 31;
  const int idx = threadIdx.x >> 5;       // 0..7
  const int n = g * 32 + coll;

  _Float16* gb = Bext + (size_t)head * NK * KB + (size_t)g * 8192;
  const float* src = emb + (size_t)head * NK * ND + (size_t)n * ND;

  #pragma unroll
  for (int iter = 0; iter < 2; ++iter) {
    const int kh = idx + iter * 8; // 0..15 half-kstep
    const int ks = kh >> 1, hi = kh & 1;
    const int k = ks * 16 + hi * 8;
    const float4* wp = (const float4*)(src + k);
    float4 v0 = wp[0], v1 = wp[1];
    float xv[8] = {v0.x, v0.y, v0.z, v0.w, v1.x, v1.y, v1.z, v1.w};
    half8_t h, l;
    #pragma unroll
    for (int j = 0; j < 8; ++j) {
      _Float16 hh = (_Float16)xv[j];
      h[j] = hh;
      l[j] = (_Float16)(xv[j] - (float)hh);
    }
    const int lanef = hi * 32 + coll;
    *(half8_t*)(gb + ks * 512 + lanef * 8) = h;       // wh
    *(half8_t*)(gb + (8 + ks) * 512 + lanef * 8) = l; // wl
  }
}

// ---------------------------------------------------------------------------
// Barrier-free score kernel — R13: R12 + rolling distance-1 B prefetch.
// R12 diagnosis: no prefetch -> each of 8 ks steps serializes ~250cy L2
// latency vs 97cy MFMA -> per-ci ~2000cy, MfmaUtil 30% (= 45.7us busy on a
// 41.3us floor over 154us wall). Fix: consume (bh,bl) while loading (nh,nl)
// for ks+1; ks7 prefetches NEXT ci's ks0 so the ~150cy fold covers that
// load too (ci==0 wraps to itself: harmless reload).
// Register ledger (the 64-VGPR cliff: >64 drops 8->6 waves/SIMD and breaks
// the 4-blocks/CU residency): R12 measured 48; prefetch adds 8 (nh/nl) + 1
// (next-ci offset) -> ~58 <= 64. acc dead at fold (R2/R4); only the 8
// prefetch regs live across it (R1's spill had 64 acc + 32 bs live).
// Geometry (R12): 8 waves = 2 row-halves x 4 col-groups, one 32x32 tile per
// wave, CI=128/NCI=16, RB=64 -> LDS 32.5 KB -> 4 blocks/CU, grid 1024 =
// exactly 4/CU tail-free; co-resident blocks share one cs (256%16==0) ->
// one 1 MB B slice per CU in L2.
// A LDS [m:64][slot:32][8f16], slot = chunk ^ (m&31); read addr =
// Q ^ ks*32 ^ src*256 (disjoint bits). Fragment maps (R9/R10 absmax=0):
// A/B lane l: row|col=l&31, k=(l>>5)*8+j; C: col=l&31,
// row=(reg&3)+8*(reg>>2)+4*(l>>5).
// Tie-break: one col per lane-slot per ci, ci descending => cidx strictly
// decreasing, ">=" keeps lowest index; cross-lane/block comparator
// (>, ==&&<) handles col ties. Matches jnp.argmax.
// bid&15 = col-split; 2 x 1 MB B slices per XCD's L2 (cs mod 8 == xcd).
__global__ __launch_bounds__(512, 4) void score_mfma_kernel(
    const _Float16* __restrict__ Aext, const _Float16* __restrict__ Bext,
    const float* __restrict__ rr, const float* __restrict__ normh,
    float* __restrict__ partial_s, int* __restrict__ partial_i) {
  __shared__ __align__(16) _Float16 Ash[RB * KA]; // 32 KB: [m:64][slot:32][8 f16]
  __shared__ __align__(16) float rrsh[RB];        // 256 B

  const int bid = blockIdx.x;
  const int cs = bid & (CS - 1);
  const int rowb = bid >> 4;
  const int rowBase = rowb * RB;
  const int colBase0 = cs * CPB;

  const int tid = threadIdx.x;
  const int lane = tid & 63;
  const int wn = tid >> 6; // wave 0..7
  const int wc = wn & 3;   // col-group (32 cols)
  const int wr = wn >> 2;  // row-half (32 rows)
  const int cl = lane & 31;
  const int hi = lane >> 5;

  // ---- stage A panel (once): wave wn stages rows wn*8..+8 (4 KB) ----
  // LDS[m][slot] = A[rowBase+m][chunk = slot ^ (m&31)]  (chunk = 8 f16)
  {
    #pragma unroll
    for (int i = 0; i < 4; ++i) {
      const int m0 = wn * 8 + i * 2;
      const int ml = m0 + hi;
      const int c = cl ^ (ml & 31);
      const _Float16* gA = Aext + (size_t)(rowBase + ml) * KA + c * 8;
      __builtin_amdgcn_global_load_lds((gu32_t*)gA, (lu32_t*)&Ash[m0 * 256], 16, 0, 0);
    }
  }
  if (tid < RB) rrsh[tid] = rr[rowBase + tid];

  // per-lane A byte address (even parity); read addr = Q ^ (ks*32) ^ (src*256)
  // addr = m*512 + (chunk ^ (m&31))*16, chunk = ks*2 + hi + src*16
  int Q;
  {
    const int ml = wr * 32 + cl;
    Q = (ml * 512 + (ml & 31) * 16) ^ (hi * 16);
  }

  float bs[16];
  int pk[2]; // 16 slots x 4-bit ci
  #pragma unroll
  for (int t = 0; t < 16; ++t) bs[t] = -INFINITY;
  pk[0] = 0;
  pk[1] = 0;

  __syncthreads(); // the only barrier before the epilogue

  const f32x16 Z = {0.f, 0.f, 0.f, 0.f, 0.f, 0.f, 0.f, 0.f,
                    0.f, 0.f, 0.f, 0.f, 0.f, 0.f, 0.f, 0.f};
  const char* AshB = (const char*)Ash;
  const char* BextB = (const char*)Bext;

  // prologue: issue B(ci = NCI-1, ks0)
  unsigned bo = (unsigned)((colBase0 + (NCI - 1) * CI + wc * 32) >> 5) * 16384u +
                (unsigned)lane * 16u;
  half8_t bh = *(const half8_t*)(BextB + bo);
  half8_t bl = *(const half8_t*)(BextB + bo + 8 * 1024);

  #pragma unroll 1
  for (int ci = NCI - 1; ci >= 0; --ci) {
    const int ncol = colBase0 + ci * CI + wc * 32;
    const int ci_n = (ci > 0) ? ci - 1 : 0;
    const unsigned bon = (unsigned)((colBase0 + ci_n * CI + wc * 32) >> 5) * 16384u +
                         (unsigned)lane * 16u;
    const float nw = normh[ncol + cl]; // issued early, used in fold

    f32x16 acc;
    half8_t nh, nl;
    // ---- ks = 0, peeled: consume preloaded bh/bl; prefetch ks1 ----
    {
      nh = *(const half8_t*)(BextB + bo + 1024);
      nl = *(const half8_t*)(BextB + bo + 9 * 1024);
      half8_t ah = *(const half8_t*)(AshB + Q);
      half8_t al = *(const half8_t*)(AshB + (Q ^ 256));
      __builtin_amdgcn_s_setprio(1);
      acc = MFMA32(ah, bh, Z);
      acc = MFMA32(al, bh, acc);
      acc = MFMA32(ah, bl, acc);
      __builtin_amdgcn_s_setprio(0);
      bh = nh;
      bl = nl;
    }
    // ---- ks = 1..7: consume ks, prefetch ks+1 (ks7 -> next ci's ks0) ----
    #pragma unroll 1
    for (int ks = 1; ks < 8; ++ks) {
      const unsigned po = (ks < 7) ? bo + (unsigned)((ks + 1) * 1024) : bon;
      nh = *(const half8_t*)(BextB + po);
      nl = *(const half8_t*)(BextB + po + 8 * 1024);
      half8_t ah = *(const half8_t*)(AshB + (Q ^ (ks * 32)));
      half8_t al = *(const half8_t*)(AshB + (Q ^ (ks * 32) ^ 256));
      __builtin_amdgcn_s_setprio(1);
      acc = MFMA32(ah, bh, acc);
      acc = MFMA32(al, bh, acc);
      acc = MFMA32(ah, bl, acc);
      __builtin_amdgcn_s_setprio(0);
      bh = nh;
      bl = nl;
    }

    // ---- fold into running argmax (index = ci packed as a nibble) ----
    // bh/bl now hold next ci's ks0 — their L2 latency hides under the fold.
    // One col per lane-slot, cidx strictly decreasing across ci, so ">="
    // keeps the lowest index, matching jnp.argmax.
    #pragma unroll
    for (int g = 0; g < 4; ++g) {
      const f32x4 r4 = *(const f32x4*)&rrsh[wr * 32 + hi * 4 + g * 8];
      #pragma unroll
      for (int j = 0; j < 4; ++j) {
        const int s = g * 4 + j;
        float t1 = r4[j] + nw;              // fl(rr + |w|^2), as ref
        float v = fmaf(2.0f, acc[s], -t1);  // == fl(2*acc - t1)
        bool u = (v >= bs[s]);
        bs[s] = u ? v : bs[s];
        const int sh = (s & 7) * 4;
        int upd = (pk[s >> 3] & ~(0xF << sh)) | (ci << sh);
        pk[s >> 3] = u ? upd : pk[s >> 3];
      }
    }
    bo = bon;
  }

  // ---- block argmax reduction (overlay scratch on Ash) ----
  __syncthreads(); // all LDS A-reads complete
  float* red_s = (float*)Ash;      // [64][4]
  int* red_i = (int*)Ash + RB * 4; // [64][4]
  const int cbase = colBase0 + wc * 32 + cl;
  #pragma unroll
  for (int s = 0; s < 16; ++s) {
    float v = bs[s];
    int ciS = (pk[s >> 3] >> ((s & 7) * 4)) & 15;
    int ii = cbase + ciS * CI;
    // reduce over the 32 cols (each 32-lane half holds disjoint rows)
    #pragma unroll
    for (int mask = 1; mask <= 16; mask <<= 1) {
      float os = __shfl_xor(v, mask, 64);
      int oi = __shfl_xor(ii, mask, 64);
      if (os > v || (os == v && oi < ii)) { v = os; ii = oi; }
    }
    if (cl == 0) {
      const int row = wr * 32 + (s & 3) + 8 * (s >> 2) + 4 * hi;
      red_s[row * 4 + wc] = v;
      red_i[row * 4 + wc] = ii;
    }
  }
  __syncthreads();
  if (tid < RB) {
    float s0 = red_s[tid * 4];
    int i0 = red_i[tid * 4];
    #pragma unroll
    for (int x = 1; x < 4; ++x) {
      float sx = red_s[tid * 4 + x];
      int ix = red_i[tid * 4 + x];
      if (sx > s0 || (sx == s0 && ix < i0)) { s0 = sx; i0 = ix; }
    }
    partial_s[(size_t)(rowBase + tid) * CS + cs] = s0;
    partial_i[(size_t)(rowBase + tid) * CS + cs] = i0;
  }
}

// ---------------------------------------------------------------------------
// Combine col-split partials -> code; resid -= W[c]; quantized += W[c];
// new rr; Aext row for next head.
__global__ __launch_bounds__(64) void reduce_update_kernel(const float* __restrict__ embh,
                                                           float* __restrict__ resid,
                                                           float* __restrict__ rr,
                                                           const float* __restrict__ ps,
                                                           const int* __restrict__ pi,
                                                           float* __restrict__ out,
                                                           _Float16* __restrict__ Aext, int h) {
  int row = blockIdx.x;
  int lane = threadIdx.x;
  float bs = -INFINITY;
  int bi = 0x7fffffff;
  if (lane < CS) {
    bs = ps[(size_t)row * CS + lane];
    bi = pi[(size_t)row * CS + lane];
  }
  #pragma unroll
  for (int m = 8; m; m >>= 1) {
    float os = __shfl_xor(bs, m, 64);
    int oi = __shfl_xor(bi, m, 64);
    if (os > bs || (os == bs && oi < bi)) { bs = os; bi = oi; }
  }
  int c = __shfl(bi, 0, 64);
  if (lane == 0) out[NB + NB * ND + row * NH + h] = (float)c; // codes as f32

  const float* wv = embh + (size_t)c * ND;
  float q0 = wv[lane], q1 = wv[lane + 64];
  float r0 = resid[row * ND + lane] - q0;
  float r1 = resid[row * ND + lane + 64] - q1;
  resid[row * ND + lane] = r0;
  resid[row * ND + lane + 64] = r1;
  out[NB + row * ND + lane] += q0;
  out[NB + row * ND + lane + 64] += q1;

  // Aext row for the next head (harmless extra work on the last head)
  _Float16 h0 = (_Float16)r0, l0 = (_Float16)(r0 - (float)h0);
  _Float16 h1 = (_Float16)r1, l1 = (_Float16)(r1 - (float)h1);
  _Float16* ab = Aext + (size_t)row * KA;
  ab[lane] = h0;       ab[lane + 64] = h1;       // rh
  ab[128 + lane] = l0; ab[128 + lane + 64] = l1; // rl

  float s = r0 * r0 + r1 * r1;
  #pragma unroll
  for (int m = 32; m; m >>= 1) s += __shfl_xor(s, m, 64);
  if (lane == 0) rr[row] = s;
}

// ---------------------------------------------------------------------------
extern "C" void kernel_launch(void* const* d_in, const int* in_sizes, int n_in,
                              void* d_out, int out_size, void* d_ws, size_t ws_size,
                              hipStream_t stream) {
  const float* inp = (const float*)d_in[0]; // (4096,1,128)
  const float* emb = (const float*)d_in[1]; // (3,32768,128)
  float* out = (float*)d_out;               // loss | quantized | codes

  float* resid = (float*)d_ws;                        // NB*ND f32
  float* rr = resid + NB * ND;                        // NB
  float* norms = rr + NB;                             // NH*NK
  float* ps = norms + NH * NK;                        // NB*CS f32
  int* pi = (int*)(ps + (size_t)NB * CS);             // NB*CS i32
  _Float16* Aext = (_Float16*)(pi + (size_t)NB * CS); // NB*KA f16
  _Float16* Bext = Aext + (size_t)NB * KA;            // NH*NK*KB f16 (~50 MB)

  hipLaunchKernelGGL(init_kernel, dim3(NB), dim3(64), 0, stream, inp, resid, rr, out, Aext);
  hipLaunchKernelGGL(norms_kernel, dim3(NH * NK / 4), dim3(256), 0, stream, emb, norms);
  hipLaunchKernelGGL(split_w_all_kernel, dim3(NH * NK / 32), dim3(256), 0, stream, emb, Bext);
  for (int h = 0; h < NH; ++h) {
    hipLaunchKernelGGL(score_mfma_kernel, dim3((NB / RB) * CS), dim3(512), 0, stream,
                       Aext, Bext + (size_t)h * NK * KB, rr, norms + (size_t)h * NK, ps, pi);
    hipLaunchKernelGGL(reduce_update_kernel, dim3(NB), dim3(64), 0, stream,
                       emb + (size_t)h * NK * ND, resid, rr, ps, pi, out, Aext, h);
  }
}

// Round 14
// 423.175 us; speedup vs baseline: 1.3659x; 1.1982x over previous
//
#include <hip/hip_runtime.h>
#include <math.h>

#define NB 4096
#define NH 3
#define NK 32768
#define ND 128
#define KA 256           // A stored K: [rh(128) | rl(128)]
#define KB 256           // B stored K: [wh(128) | wl(128)]  (dedup: wh read twice via regs)
#define RB 64            // rows per block (32.5 KB LDS -> 4 blocks/CU resident)
#define CS 16            // column splits (2 per XCD)
#define CPB (NK / CS)    // 2048 cols per block
#define CI 128           // cols per col-iteration (4 waves x 32)
#define NCI (CPB / CI)   // 16 col-iterations per block

typedef _Float16 half8_t __attribute__((ext_vector_type(8)));
typedef _Float16 half2_t __attribute__((ext_vector_type(2)));
typedef float f32x4 __attribute__((ext_vector_type(4)));
typedef __attribute__((address_space(1))) const unsigned int gu32_t;
typedef __attribute__((address_space(3))) unsigned int lu32_t;

// ---------------------------------------------------------------------------
// init: resid = inputs, quantized = 0, loss = 0, rr = sum(resid^2), Aext row.
__global__ __launch_bounds__(64) void init_kernel(const float* __restrict__ inp,
                                                  float* __restrict__ resid,
                                                  float* __restrict__ rr,
                                                  float* __restrict__ out,
                                                  _Float16* __restrict__ Aext) {
  int row = blockIdx.x;
  int lane = threadIdx.x;
  const float2* ip = (const float2*)(inp + row * ND);
  float2 v = ip[lane];
  ((float2*)(resid + row * ND))[lane] = v;
  ((float2*)(out + NB + row * ND))[lane] = make_float2(0.f, 0.f);
  if (lane == 0) out[row] = 0.f; // loss
  _Float16 h0 = (_Float16)v.x, h1 = (_Float16)v.y;
  _Float16 l0 = (_Float16)(v.x - (float)h0), l1 = (_Float16)(v.y - (float)h1);
  half2_t h = {h0, h1}, l = {l0, l1};
  _Float16* base = Aext + (size_t)row * KA;
  *(half2_t*)(base + 2 * lane) = h;       // rh
  *(half2_t*)(base + 128 + 2 * lane) = l; // rl
  float s = v.x * v.x + v.y * v.y;
  #pragma unroll
  for (int m = 32; m; m >>= 1) s += __shfl_xor(s, m, 64);
  if (lane == 0) rr[row] = s;
}

// ---------------------------------------------------------------------------
// norms[row] = sum(W[row]^2) for all H*K rows (one wave per row), fp32 exact.
// NOTE: do NOT change this reduction tree — its rounding order is what the
// reference-matching argmax ties were validated against.
__global__ __launch_bounds__(256) void norms_kernel(const float* __restrict__ emb,
                                                    float* __restrict__ norms) {
  int row = blockIdx.x * 4 + (threadIdx.x >> 6);
  int lane = threadIdx.x & 63;
  const float2* wp = (const float2*)(emb + (size_t)row * ND);
  float2 v = wp[lane];
  float s = v.x * v.x + v.y * v.y;
  #pragma unroll
  for (int m = 32; m; m >>= 1) s += __shfl_xor(s, m, 64);
  if (lane == 0) norms[row] = s;
}

// ---------------------------------------------------------------------------
// fp32 -> (hi,lo) fp16 split, ALL heads at once (emb is static), into the
// 16x16x32 kstep-major fragment layout WITHOUT the wh duplicate:
//   f16 offset = head*NK*KB + col64*16384 + ks*2048 + sub*512 + klo*128 + n_lo*8 + j
// ks 0..3 = wh chunks (k 0..127), ks 4..7 = wl chunks.
__global__ __launch_bounds__(256) void split_w_all_kernel(const float* __restrict__ emb,
                                                          _Float16* __restrict__ Bext) {
  const int head = blockIdx.x >> 11;      // 0..2
  const int cg = blockIdx.x & 2047;       // col group 0..2047 (16 cols each)
  const int n_lo = threadIdx.x & 15;
  const int c = threadIdx.x >> 4;         // 8-elem k-chunk 0..15 (k = c*8..)
  const int n = cg * 16 + n_lo;

  const float4* wp = (const float4*)(emb + (size_t)head * NK * ND + (size_t)n * ND + c * 8);
  float4 v0 = wp[0], v1 = wp[1];
  float xv[8] = {v0.x, v0.y, v0.z, v0.w, v1.x, v1.y, v1.z, v1.w};
  half8_t h, l;
  #pragma unroll
  for (int j = 0; j < 8; ++j) {
    _Float16 hh = (_Float16)xv[j];
    h[j] = hh;
    l[j] = (_Float16)(xv[j] - (float)hh);
  }
  const int ks0 = c >> 2; // 32-k chunk 0..3
  const int klo = c & 3;  // 8-chunk within the 32-k step
  _Float16* base = Bext + (size_t)head * NK * KB + (size_t)(cg >> 2) * 16384 +
                   (cg & 3) * 512 + klo * 128 + n_lo * 8;
  *(half8_t*)(base + ks0 * 2048) = h;       // wh  (ks 0..3)
  *(half8_t*)(base + (4 + ks0) * 2048) = l; // wl  (ks 4..7)
}

// ---------------------------------------------------------------------------
// Barrier-free score kernel — R14: champion wave shape (R8: 64r x 32c,
// 16x16x32, acc[4][2]) at 256 threads with rolling B prefetch.
// Why: R8 (97.7us) shows MfmaUtil 49 + VALUBusy 44 ~= wall — pipes don't
// overlap; per-ci the kc0 B load (~250cy) and fold tail serialize, aligned
// across waves. R13 proved rolling distance-1 prefetch (+across-ci: fold
// covers next ci's kc0) helps and costs ~16 regs — but R8's (512,4) config
// empirically caps the allocator at 64 VGPR (R8 fit EXACTLY; R9/R11's
// +anything spilled). (256,2) measured 92-108 spill-free (R0/R5-R7).
// So: 256 thr, 4 waves each 64r x 32c (wave wn = col-group), RB=64 ->
// LDS 32.5 KB -> 4 blocks/CU -> 4 waves/SIMD (= R8's TLP); grid 1024 =
// exactly 4/CU tail-free; co-resident blocks share one cs (256%16==0).
// Register ledger (target <=128 for 4 waves/SIMD): acc 32 + bs 16 + bi 16
// + B cur 16 + B next 16 + A(per-mt) 8 + aaddr0 4 + misc ~10 ~= 118.
// rv -> rrsh LDS (identical f32 values, rounding unchanged); aaddr odd
// parity = even ^ 64 (R5-verified); kc0 Z-peel kills the 32-mov acc init.
// B dedup: per 32-k chunk kc, 4 B loads feed 24 MFMAs; wh feeds TWO sets
// (A=rh, A=rl), wl one (A=rh). All numerics/tie-break byte-identical to
// the verified R0/R8 fold: ci desc + tn desc => cols strictly decreasing,
// ">=" keeps lowest index (matches jnp.argmax).
// bid&15 = col-split; 2 x 1 MB B slices per XCD's L2 (cs mod 8 == xcd).
__global__ __launch_bounds__(256, 2) void score_mfma_kernel(
    const _Float16* __restrict__ Aext, const _Float16* __restrict__ Bext,
    const float* __restrict__ rr, const float* __restrict__ normh,
    float* __restrict__ partial_s, int* __restrict__ partial_i) {
  __shared__ __align__(16) _Float16 Ash[RB * KA]; // 32 KB
  __shared__ __align__(16) float rrsh[RB];        // 256 B

  const int bid = blockIdx.x;
  const int cs = bid & (CS - 1);
  const int rowb = bid >> 4;
  const int rowBase = rowb * RB;
  const int colBase0 = cs * CPB;

  const int tid = threadIdx.x;
  const int lane = tid & 63;
  const int wn = tid >> 6; // wave = col group 0..3
  const int l15 = lane & 15;
  const int q = lane >> 4;

  // ---- stage A panel [rh|rl] (once) — R0-verified staging ----
  {
    const int mrow = lane >> 3;             // 0..7 within 8-row group
    const int cg = (lane & 7) ^ (mrow & 7); // chunk this lane fetches
    #pragma unroll
    for (int i = 0; i < 8; ++i) {
      int wc = wn * 8 + i; // 0..31 wave-chunks (1 KB each)
      int p = wc >> 3;     // panel 0..3 (64 k each)
      int m0 = (wc & 7) * 8;
      const _Float16* gA = Aext + (size_t)(rowBase + m0 + mrow) * KA + p * 64 + cg * 8;
      __builtin_amdgcn_global_load_lds((gu32_t*)gA, (lu32_t*)&Ash[(p * 64 + m0) * 64], 16, 0, 0);
    }
  }
  if (tid < RB) rrsh[tid] = rr[rowBase + tid];

  // per-lane A-fragment LDS byte addresses, even-kc parity (odd = ^64):
  // slot=(par*4+q)^(m&7); par flips byte bit6 carry-free (R5-verified).
  int aaddr0[4];
  #pragma unroll
  for (int mt = 0; mt < 4; ++mt) {
    int m = mt * 16 + l15;
    int slot = q ^ (m & 7);
    aaddr0[mt] = (m * 8 + slot) * 16; // bytes
  }

  float bs[16];
  int bi[16];
  #pragma unroll
  for (int t = 0; t < 16; ++t) { bs[t] = -INFINITY; bi[t] = 0x7fffffff; }

  // prologue: issue B(ci = NCI-1, kc0) — flies during the barrier
  unsigned bo = (unsigned)((colBase0 + (NCI - 1) * CI + wn * 32) >> 6) * 16384u +
                (((unsigned)(colBase0 + (NCI - 1) * CI + wn * 32) >> 4) & 3u) * 512u +
                (unsigned)lane * 8u;
  half8_t bh[2], bl[2];
  #pragma unroll
  for (int tn = 0; tn < 2; ++tn) {
    bh[tn] = *(const half8_t*)(Bext + bo + (unsigned)(tn * 512));
    bl[tn] = *(const half8_t*)(Bext + bo + (unsigned)(8192 + tn * 512));
  }

  __syncthreads(); // the only barrier before the epilogue

  const f32x4 Z = {0.f, 0.f, 0.f, 0.f};

  #pragma unroll 1
  for (int ci = NCI - 1; ci >= 0; --ci) {
    const int ncol = colBase0 + ci * CI + wn * 32;
    const int ci_n = (ci > 0) ? ci - 1 : 0;
    const int ncol_n = colBase0 + ci_n * CI + wn * 32;
    const unsigned bon = (unsigned)(ncol_n >> 6) * 16384u +
                         (((unsigned)ncol_n >> 4) & 3u) * 512u + (unsigned)lane * 8u;

    // normh for this ci, issued early; consumed by the fold at ci end
    float nw[2];
    #pragma unroll
    for (int tn = 0; tn < 2; ++tn) nw[tn] = normh[ncol + tn * 16 + l15];

    f32x4 acc[4][2];
    half8_t nh[2], nl[2];

    // ---- kc = 0, peeled: consume preloaded bh/bl with Z C-in; prefetch kc1
    {
      #pragma unroll
      for (int tn = 0; tn < 2; ++tn) {
        nh[tn] = *(const half8_t*)(Bext + bo + (unsigned)(2048 + tn * 512));
        nl[tn] = *(const half8_t*)(Bext + bo + (unsigned)(2048 + 8192 + tn * 512));
      }
      __builtin_amdgcn_s_setprio(1);
      #pragma unroll
      for (int mt = 0; mt < 4; ++mt) {
        half8_t ah = *(const half8_t*)((const char*)Ash + aaddr0[mt]);
        half8_t al = *(const half8_t*)((const char*)Ash + aaddr0[mt] + 16384);
        acc[mt][0] = __builtin_amdgcn_mfma_f32_16x16x32_f16(ah, bh[0], Z, 0, 0, 0);
        acc[mt][1] = __builtin_amdgcn_mfma_f32_16x16x32_f16(ah, bh[1], Z, 0, 0, 0);
        acc[mt][0] = __builtin_amdgcn_mfma_f32_16x16x32_f16(al, bh[0], acc[mt][0], 0, 0, 0);
        acc[mt][1] = __builtin_amdgcn_mfma_f32_16x16x32_f16(al, bh[1], acc[mt][1], 0, 0, 0);
        acc[mt][0] = __builtin_amdgcn_mfma_f32_16x16x32_f16(ah, bl[0], acc[mt][0], 0, 0, 0);
        acc[mt][1] = __builtin_amdgcn_mfma_f32_16x16x32_f16(ah, bl[1], acc[mt][1], 0, 0, 0);
      }
      __builtin_amdgcn_s_setprio(0);
      bh[0] = nh[0]; bh[1] = nh[1];
      bl[0] = nl[0]; bl[1] = nl[1];
    }

    // ---- kc = 1..3: consume kc, prefetch kc+1 (kc3 -> next ci's kc0) ----
    #pragma unroll
    for (int kc = 1; kc < 4; ++kc) {
      const unsigned po = (kc < 3) ? bo + (unsigned)((kc + 1) * 2048) : bon;
      #pragma unroll
      for (int tn = 0; tn < 2; ++tn) {
        nh[tn] = *(const half8_t*)(Bext + po + (unsigned)(tn * 512));
        nl[tn] = *(const half8_t*)(Bext + po + (unsigned)(8192 + tn * 512));
      }
      const int axor = (kc & 1) << 6;
      const int abase = (kc >> 1) * 8192;
      __builtin_amdgcn_s_setprio(1);
      #pragma unroll
      for (int mt = 0; mt < 4; ++mt) {
        half8_t ah = *(const half8_t*)((const char*)Ash + ((aaddr0[mt] ^ axor) + abase));
        half8_t al = *(const half8_t*)((const char*)Ash + ((aaddr0[mt] ^ axor) + abase + 16384));
        acc[mt][0] = __builtin_amdgcn_mfma_f32_16x16x32_f16(ah, bh[0], acc[mt][0], 0, 0, 0);
        acc[mt][1] = __builtin_amdgcn_mfma_f32_16x16x32_f16(ah, bh[1], acc[mt][1], 0, 0, 0);
        acc[mt][0] = __builtin_amdgcn_mfma_f32_16x16x32_f16(al, bh[0], acc[mt][0], 0, 0, 0);
        acc[mt][1] = __builtin_amdgcn_mfma_f32_16x16x32_f16(al, bh[1], acc[mt][1], 0, 0, 0);
        acc[mt][0] = __builtin_amdgcn_mfma_f32_16x16x32_f16(ah, bl[0], acc[mt][0], 0, 0, 0);
        acc[mt][1] = __builtin_amdgcn_mfma_f32_16x16x32_f16(ah, bl[1], acc[mt][1], 0, 0, 0);
      }
      __builtin_amdgcn_s_setprio(0);
      bh[0] = nh[0]; bh[1] = nh[1];
      bl[0] = nl[0]; bl[1] = nl[1];
    }

    // ---- fold into running argmax; next ci's kc0 B loads are in flight
    // underneath (their L2 latency hides here). tn DESC + ci DESC => cols
    // strictly decreasing, ">=" keeps the lowest index on ties.
    #pragma unroll
    for (int tn = 1; tn >= 0; --tn) {
      const float nwv = nw[tn];
      const int cidx = ncol + tn * 16 + l15;
      #pragma unroll
      for (int mt = 0; mt < 4; ++mt) {
        const f32x4 rvv = *(const f32x4*)&rrsh[mt * 16 + q * 4];
        #pragma unroll
        for (int reg = 0; reg < 4; ++reg) {
          const int s = mt * 4 + reg;
          float t1 = rvv[reg] + nwv;                   // fl(rr + |w|^2), as ref
          float v = fmaf(2.0f, acc[mt][tn][reg], -t1); // == fl(2*acc - t1)
          if (v >= bs[s]) { bs[s] = v; bi[s] = cidx; }
        }
      }
    }
    bo = bon;
  }

  // ---- block argmax reduction (overlay scratch on Ash) ----
  __syncthreads(); // all LDS A-reads complete
  float* red_s = (float*)Ash;      // [64][4]
  int* red_i = (int*)Ash + RB * 4; // [64][4]
  #pragma unroll
  for (int t = 0; t < 16; ++t) {
    float s = bs[t];
    int ii = bi[t];
    #pragma unroll
    for (int mask = 1; mask <= 8; mask <<= 1) {
      float os = __shfl_xor(s, mask, 64);
      int oi = __shfl_xor(ii, mask, 64);
      if (os > s || (os == s && oi < ii)) { s = os; ii = oi; }
    }
    if (l15 == 0) {
      int rloc = (t >> 2) * 16 + q * 4 + (t & 3); // mt*16 + q*4 + reg
      red_s[rloc * 4 + wn] = s;
      red_i[rloc * 4 + wn] = ii;
    }
  }
  __syncthreads();
  if (tid < RB) {
    float s0 = red_s[tid * 4];
    int i0 = red_i[tid * 4];
    #pragma unroll
    for (int x = 1; x < 4; ++x) {
      float sx = red_s[tid * 4 + x];
      int ix = red_i[tid * 4 + x];
      if (sx > s0 || (sx == s0 && ix < i0)) { s0 = sx; i0 = ix; }
    }
    partial_s[(size_t)(rowBase + tid) * CS + cs] = s0;
    partial_i[(size_t)(rowBase + tid) * CS + cs] = i0;
  }
}

// ---------------------------------------------------------------------------
// Combine col-split partials -> code; resid -= W[c]; quantized += W[c];
// new rr; Aext row for next head.
__global__ __launch_bounds__(64) void reduce_update_kernel(const float* __restrict__ embh,
                                                           float* __restrict__ resid,
                                                           float* __restrict__ rr,
                                                           const float* __restrict__ ps,
                                                           const int* __restrict__ pi,
                                                           float* __restrict__ out,
                                                           _Float16* __restrict__ Aext, int h) {
  int row = blockIdx.x;
  int lane = threadIdx.x;
  float bs = -INFINITY;
  int bi = 0x7fffffff;
  if (lane < CS) {
    bs = ps[(size_t)row * CS + lane];
    bi = pi[(size_t)row * CS + lane];
  }
  #pragma unroll
  for (int m = 8; m; m >>= 1) {
    float os = __shfl_xor(bs, m, 64);
    int oi = __shfl_xor(bi, m, 64);
    if (os > bs || (os == bs && oi < bi)) { bs = os; bi = oi; }
  }
  int c = __shfl(bi, 0, 64);
  if (lane == 0) out[NB + NB * ND + row * NH + h] = (float)c; // codes as f32

  const float* wv = embh + (size_t)c * ND;
  float q0 = wv[lane], q1 = wv[lane + 64];
  float r0 = resid[row * ND + lane] - q0;
  float r1 = resid[row * ND + lane + 64] - q1;
  resid[row * ND + lane] = r0;
  resid[row * ND + lane + 64] = r1;
  out[NB + row * ND + lane] += q0;
  out[NB + row * ND + lane + 64] += q1;

  // Aext row for the next head (harmless extra work on the last head)
  _Float16 h0 = (_Float16)r0, l0 = (_Float16)(r0 - (float)h0);
  _Float16 h1 = (_Float16)r1, l1 = (_Float16)(r1 - (float)h1);
  _Float16* ab = Aext + (size_t)row * KA;
  ab[lane] = h0;       ab[lane + 64] = h1;       // rh
  ab[128 + lane] = l0; ab[128 + lane + 64] = l1; // rl

  float s = r0 * r0 + r1 * r1;
  #pragma unroll
  for (int m = 32; m; m >>= 1) s += __shfl_xor(s, m, 64);
  if (lane == 0) rr[row] = s;
}

// ---------------------------------------------------------------------------
extern "C" void kernel_launch(void* const* d_in, const int* in_sizes, int n_in,
                              void* d_out, int out_size, void* d_ws, size_t ws_size,
                              hipStream_t stream) {
  const float* inp = (const float*)d_in[0]; // (4096,1,128)
  const float* emb = (const float*)d_in[1]; // (3,32768,128)
  float* out = (float*)d_out;               // loss | quantized | codes

  float* resid = (float*)d_ws;                        // NB*ND f32
  float* rr = resid + NB * ND;                        // NB
  float* norms = rr + NB;                             // NH*NK
  float* ps = norms + NH * NK;                        // NB*CS f32
  int* pi = (int*)(ps + (size_t)NB * CS);             // NB*CS i32
  _Float16* Aext = (_Float16*)(pi + (size_t)NB * CS); // NB*KA f16
  _Float16* Bext = Aext + (size_t)NB * KA;            // NH*NK*KB f16 (~50 MB)

  hipLaunchKernelGGL(init_kernel, dim3(NB), dim3(64), 0, stream, inp, resid, rr, out, Aext);
  hipLaunchKernelGGL(norms_kernel, dim3(NH * NK / 4), dim3(256), 0, stream, emb, norms);
  hipLaunchKernelGGL(split_w_all_kernel, dim3(NH * NK / 16), dim3(256), 0, stream, emb, Bext);
  for (int h = 0; h < NH; ++h) {
    hipLaunchKernelGGL(score_mfma_kernel, dim3((NB / RB) * CS), dim3(256), 0, stream,
                       Aext, Bext + (size_t)h * NK * KB, rr, norms + (size_t)h * NK, ps, pi);
    hipLaunchKernelGGL(reduce_update_kernel, dim3(NB), dim3(64), 0, stream,
                       emb + (size_t)h * NK * ND, resid, rr, ps, pi, out, Aext, h);
  }
}